// Round 1
// baseline (479.971 us; speedup 1.0000x reference)
//
#include <hip/hip_runtime.h>
#include <hip/hip_bf16.h>

#define B_    32
#define C_    256
#define H_    56
#define W_    56
#define HW_   3136
#define P_    58          // padded spatial (halo of 1)
#define G_    8
#define COUT_ 256
#define KTOT_ 2304        // 256 * 9

typedef _Float16 h16;
typedef _Float16 half8 __attribute__((ext_vector_type(8)));
typedef float    f32x4 __attribute__((ext_vector_type(4)));

// ---------------------------------------------------------------------------
// Kernel 1: GroupNorm statistics. One block per (b,g); group data is
// contiguous in NCHW (32 consecutive channels). 256 blocks x 256 threads.
// ---------------------------------------------------------------------------
__global__ __launch_bounds__(256)
void gn_stats_kernel(const float* __restrict__ x, float* __restrict__ stats) {
    int bg = blockIdx.x;                       // b*8 + g
    const float4* base = (const float4*)(x + (size_t)bg * (32 * HW_));
    float s1 = 0.f, s2 = 0.f;
    for (int i = threadIdx.x; i < 25088; i += 256) {   // 100352 floats / 4
        float4 v = base[i];
        s1 += v.x + v.y + v.z + v.w;
        s2 += v.x * v.x + v.y * v.y + v.z * v.z + v.w * v.w;
    }
    #pragma unroll
    for (int off = 32; off; off >>= 1) {
        s1 += __shfl_down(s1, off, 64);
        s2 += __shfl_down(s2, off, 64);
    }
    __shared__ float ra[4], rb[4];
    int lane = threadIdx.x & 63, wv = threadIdx.x >> 6;
    if (!lane) { ra[wv] = s1; rb[wv] = s2; }
    __syncthreads();
    if (threadIdx.x == 0) {
        float t1 = ra[0] + ra[1] + ra[2] + ra[3];
        float t2 = rb[0] + rb[1] + rb[2] + rb[3];
        float mu = t1 / 100352.f;
        float var = t2 / 100352.f - mu * mu;
        stats[bg * 2]     = mu;
        stats[bg * 2 + 1] = rsqrtf(var + 1e-5f);
    }
}

// ---------------------------------------------------------------------------
// Kernel 2: GN + ReLU^2 + PACT quant -> zero-padded NHWC fp16 "q" buffer.
// q holds INTEGERS 0..255 (exact in fp16). One block per (b, padded-row y);
// thread = channel. Halo rows/cols written to 0 so the GEMM needs no masks.
// ---------------------------------------------------------------------------
__global__ __launch_bounds__(256)
void act_kernel(const float* __restrict__ x, const float* __restrict__ gamma,
                const float* __restrict__ beta, const float* __restrict__ a_ptr,
                const float* __restrict__ stats, h16* __restrict__ q) {
    int by = blockIdx.x;                 // b*58 + y
    int b = by / P_;
    int y = by - b * P_;
    h16* qrow = q + (size_t)by * P_ * C_;
    if (y == 0 || y == P_ - 1) {
        for (int i = threadIdx.x; i < P_ * C_; i += 256) qrow[i] = (h16)0.f;
        return;
    }
    int c = threadIdx.x;
    float a_c = fmaxf(a_ptr[0], 0.f) + 1e-8f;
    float S   = 255.f / a_c;
    int g = c >> 5;
    float mu = stats[(b * G_ + g) * 2];
    float rs = stats[(b * G_ + g) * 2 + 1];
    float ga = gamma[c], be = beta[c];
    qrow[c] = (h16)0.f;                          // left halo col
    qrow[(P_ - 1) * C_ + c] = (h16)0.f;          // right halo col
    const float* xrow = x + ((size_t)(b * C_ + c)) * HW_ + (y - 1) * W_;
    for (int w = 0; w < W_; ++w) {
        float v  = xrow[w];
        float yv = (v - mu) * rs * ga + be;
        float r  = fmaxf(yv, 0.f);
        float h2 = fminf(r * r, a_c);
        qrow[(w + 1) * C_ + c] = (h16)rintf(h2 * S);
    }
}

// ---------------------------------------------------------------------------
// Kernel 3: ternary weight prep. One block per oc. Writes wt[tap][oc][ic]
// (B^T / K-contiguous layout, values in {-1,0,+1}) and alpha[oc].
// ---------------------------------------------------------------------------
__global__ __launch_bounds__(256)
void wq_kernel(const float* __restrict__ wfp, h16* __restrict__ wt,
               float* __restrict__ alphas) {
    int oc = blockIdx.x;
    int t  = threadIdx.x;
    const float* wr = wfp + (size_t)oc * KTOT_;
    float wl[9];
    float s = 0.f;
    #pragma unroll
    for (int j = 0; j < 9; ++j) { wl[j] = wr[t + j * 256]; s += fabsf(wl[j]); }

    __shared__ float red[4];
    int lane = t & 63, wv = t >> 6;
    // reduce sum |w|
    #pragma unroll
    for (int off = 32; off; off >>= 1) s += __shfl_down(s, off, 64);
    if (!lane) red[wv] = s;
    __syncthreads();
    float thr = 0.05f * ((red[0] + red[1] + red[2] + red[3]) / (float)KTOT_);
    __syncthreads();

    float sm = 0.f, cnt = 0.f;
    #pragma unroll
    for (int j = 0; j < 9; ++j) {
        float aw = fabsf(wl[j]);
        if (aw > thr) { sm += aw; cnt += 1.f; }
    }
    #pragma unroll
    for (int off = 32; off; off >>= 1) {
        sm  += __shfl_down(sm, off, 64);
        cnt += __shfl_down(cnt, off, 64);
    }
    __shared__ float redc[4];
    if (!lane) { red[wv] = sm; redc[wv] = cnt; }
    __syncthreads();
    if (t == 0) {
        float alpha = (red[0] + red[1] + red[2] + red[3]) /
                      (redc[0] + redc[1] + redc[2] + redc[3] + 1e-8f);
        alphas[oc] = alpha;
    }
    #pragma unroll
    for (int j = 0; j < 9; ++j) {
        int i  = t + j * 256;           // i = ic*9 + tap
        int ic = i / 9;
        int tap = i - ic * 9;
        float w = wl[j];
        float tern = (fabsf(w) > thr) ? (w > 0.f ? 1.f : -1.f) : 0.f;
        wt[((size_t)tap * 256 + oc) * 256 + ic] = (h16)tern;
    }
}

// ---------------------------------------------------------------------------
// Kernel 4: implicit-GEMM conv. M=100352 (b,h,w), N=256 (oc), K=9*256.
// 128x128 block tile, BK=64, 4 waves (2x2 of 64x64), 16x16x32 f16 MFMA.
// Staging via global_load_lds width=16. Integer-exact accumulation.
// ---------------------------------------------------------------------------
__global__ __launch_bounds__(256)
void conv_gemm_kernel(const h16* __restrict__ q, const h16* __restrict__ wt,
                      const float* __restrict__ alphas, const float* __restrict__ bias,
                      const float* __restrict__ a_ptr, float* __restrict__ out) {
    int bid = blockIdx.x;
    int nt = bid & 1;            // 2 N-tiles of 128
    int mt = bid >> 1;           // 784 M-tiles of 128
    int tid = threadIdx.x;
    int lane = tid & 63;
    int wv = tid >> 6;
    int wm = wv & 1, wn = wv >> 1;
    int quad = lane >> 4, lrow = lane & 15;

    __shared__ h16 As[128 * 64];
    __shared__ h16 Bs[128 * 64];

    int kpart = (tid & 7) * 8;
    int sb[4], wb[4];
    #pragma unroll
    for (int r = 0; r < 4; ++r) {
        int ml = r * 32 + (tid >> 3);
        int m = mt * 128 + ml;
        int b = m / HW_;
        int rem = m - b * HW_;
        int hh = rem / W_;
        int ww = rem - hh * W_;
        sb[r] = ((b * P_ + hh + 1) * P_ + (ww + 1)) * C_ + kpart;
        wb[r] = (nt * 128 + ml) * C_ + kpart;
    }

    f32x4 acc[4][4];
    #pragma unroll
    for (int i = 0; i < 4; ++i)
        #pragma unroll
        for (int j = 0; j < 4; ++j) { acc[i][j][0]=0.f; acc[i][j][1]=0.f; acc[i][j][2]=0.f; acc[i][j][3]=0.f; }

    for (int kk = 0; kk < 36; ++kk) {
        int tap = kk >> 2;
        int ic0 = (kk & 3) << 6;
        int dh = tap / 3 - 1;
        int dw = tap - (tap / 3) * 3 - 1;
        int aoff = (dh * P_ + dw) * C_ + ic0;
        const h16* gb = wt + (size_t)tap * (256 * 256) + ic0;
        #pragma unroll
        for (int r = 0; r < 4; ++r) {
            __builtin_amdgcn_global_load_lds(
                (const __attribute__((address_space(1))) void*)(q + sb[r] + aoff),
                (__attribute__((address_space(3))) void*)(&As[r * 2048 + tid * 8]),
                16, 0, 0);
        }
        #pragma unroll
        for (int r = 0; r < 4; ++r) {
            __builtin_amdgcn_global_load_lds(
                (const __attribute__((address_space(1))) void*)(gb + wb[r]),
                (__attribute__((address_space(3))) void*)(&Bs[r * 2048 + tid * 8]),
                16, 0, 0);
        }
        __syncthreads();
        #pragma unroll
        for (int ks = 0; ks < 2; ++ks) {
            int k0 = ks * 32 + quad * 8;
            half8 af[4], bf[4];
            #pragma unroll
            for (int mi = 0; mi < 4; ++mi)
                af[mi] = *(const half8*)&As[(wm * 64 + mi * 16 + lrow) * 64 + k0];
            #pragma unroll
            for (int ni = 0; ni < 4; ++ni)
                bf[ni] = *(const half8*)&Bs[(wn * 64 + ni * 16 + lrow) * 64 + k0];
            #pragma unroll
            for (int mi = 0; mi < 4; ++mi)
                #pragma unroll
                for (int ni = 0; ni < 4; ++ni)
                    acc[mi][ni] = __builtin_amdgcn_mfma_f32_16x16x32_f16(
                        af[mi], bf[ni], acc[mi][ni], 0, 0, 0);
        }
        __syncthreads();
    }

    float a_c = fmaxf(a_ptr[0], 0.f) + 1e-8f;
    float qs  = a_c * (1.f / 255.f);
    #pragma unroll
    for (int ni = 0; ni < 4; ++ni) {
        int n = nt * 128 + wn * 64 + ni * 16 + lrow;
        float sc = alphas[n] * qs;
        float bn = bias[n];
        #pragma unroll
        for (int mi = 0; mi < 4; ++mi) {
            int mbase = mt * 128 + wm * 64 + mi * 16 + quad * 4;
            int b = mbase / HW_;
            size_t off = (size_t)b * (C_ * HW_) + (size_t)n * HW_ + (mbase - b * HW_);
            f32x4 v;
            #pragma unroll
            for (int r = 0; r < 4; ++r) v[r] = acc[mi][ni][r] * sc + bn;
            *(f32x4*)(out + off) = v;
        }
    }
}

// ---------------------------------------------------------------------------
extern "C" void kernel_launch(void* const* d_in, const int* in_sizes, int n_in,
                              void* d_out, int out_size, void* d_ws, size_t ws_size,
                              hipStream_t stream) {
    const float* x     = (const float*)d_in[0];
    const float* gamma = (const float*)d_in[1];
    const float* beta  = (const float*)d_in[2];
    const float* a     = (const float*)d_in[3];
    const float* wfp   = (const float*)d_in[4];
    const float* bias  = (const float*)d_in[5];
    float* out = (float*)d_out;

    char* ws = (char*)d_ws;
    h16*  qbuf   = (h16*)ws;                                   // 32*58*58*256 fp16 = 55,115,776 B
    h16*  wtb    = (h16*)(ws + 55115776);                      // 9*256*256 fp16  = 1,179,648 B
    float* alphas = (float*)(ws + 55115776 + 1179648);         // 256 fp32
    float* stats  = alphas + 256;                              // 512 fp32 (mu, rs)

    gn_stats_kernel<<<B_ * G_, 256, 0, stream>>>(x, stats);
    wq_kernel<<<COUT_, 256, 0, stream>>>(wfp, wtb, alphas);
    act_kernel<<<B_ * P_, 256, 0, stream>>>(x, gamma, beta, a, stats, qbuf);
    conv_gemm_kernel<<<784 * 2, 256, 0, stream>>>(qbuf, wtb, alphas, bias, a, out);
}

// Round 2
// 423.955 us; speedup vs baseline: 1.1321x; 1.1321x over previous
//
#include <hip/hip_runtime.h>
#include <hip/hip_bf16.h>

#define B_    32
#define C_    256
#define H_    56
#define W_    56
#define HW_   3136
#define P_    58          // padded spatial (halo of 1)
#define G_    8
#define COUT_ 256
#define KTOT_ 2304        // 256 * 9

typedef _Float16 h16;
typedef _Float16 half8 __attribute__((ext_vector_type(8)));
typedef _Float16 h16x4 __attribute__((ext_vector_type(4)));
typedef float    f32x4 __attribute__((ext_vector_type(4)));

// ---------------------------------------------------------------------------
// Kernel 1: GroupNorm statistics. One block per (b,g); group data is
// contiguous in NCHW (32 consecutive channels). 256 blocks x 256 threads.
// ---------------------------------------------------------------------------
__global__ __launch_bounds__(256)
void gn_stats_kernel(const float* __restrict__ x, float* __restrict__ stats) {
    int bg = blockIdx.x;                       // b*8 + g
    const float4* base = (const float4*)(x + (size_t)bg * (32 * HW_));
    float s1 = 0.f, s2 = 0.f;
    for (int i = threadIdx.x; i < 25088; i += 256) {   // 100352 floats / 4
        float4 v = base[i];
        s1 += v.x + v.y + v.z + v.w;
        s2 += v.x * v.x + v.y * v.y + v.z * v.z + v.w * v.w;
    }
    #pragma unroll
    for (int off = 32; off; off >>= 1) {
        s1 += __shfl_down(s1, off, 64);
        s2 += __shfl_down(s2, off, 64);
    }
    __shared__ float ra[4], rb[4];
    int lane = threadIdx.x & 63, wv = threadIdx.x >> 6;
    if (!lane) { ra[wv] = s1; rb[wv] = s2; }
    __syncthreads();
    if (threadIdx.x == 0) {
        float t1 = ra[0] + ra[1] + ra[2] + ra[3];
        float t2 = rb[0] + rb[1] + rb[2] + rb[3];
        float mu = t1 / 100352.f;
        float var = t2 / 100352.f - mu * mu;
        stats[bg * 2]     = mu;
        stats[bg * 2 + 1] = rsqrtf(var + 1e-5f);
    }
}

// ---------------------------------------------------------------------------
// Kernel 2 (v2): GN + ReLU^2 + PACT quant -> zero-padded NHWC fp16 q buffer.
// Coalesced float4 reads of x (wave = 4 channels x 14 float4-lanes), LDS
// transpose tile T[c][64] with +c rotation swizzle on 4-column blocks,
// coalesced 512B-contiguous output rows.
// ---------------------------------------------------------------------------
__global__ __launch_bounds__(256)
void act_kernel(const float* __restrict__ x, const float* __restrict__ gamma,
                const float* __restrict__ beta, const float* __restrict__ a_ptr,
                const float* __restrict__ stats, h16* __restrict__ q) {
    int by = blockIdx.x;                 // b*58 + y
    int b = by / P_;
    int y = by - b * P_;
    h16* qrow = q + (size_t)by * P_ * C_;
    if (y == 0 || y == P_ - 1) {
        for (int i = threadIdx.x; i < P_ * C_; i += 256) qrow[i] = (h16)0.f;
        return;
    }
    __shared__ h16 T[256][64];           // [channel][w-blocks, rotated]

    int t = threadIdx.x;
    float a_c = fmaxf(a_ptr[0], 0.f) + 1e-8f;
    float S   = 255.f / a_c;

    int j  = t & 15;                     // float4 index along w (0..13 active)
    int cb = t >> 4;                     // channel sub-block 0..15
    #pragma unroll 4
    for (int iter = 0; iter < 16; ++iter) {
        int ci = iter * 16 + cb;
        if (j < 14) {
            int g = ci >> 5;
            float mu = stats[(b * G_ + g) * 2];
            float rs = stats[(b * G_ + g) * 2 + 1];
            float ga = gamma[ci], be = beta[ci];
            const float4* xr = (const float4*)(x + ((size_t)(b * C_ + ci)) * HW_ + (y - 1) * W_);
            float4 v = xr[j];
            h16x4 o;
            float f[4] = {v.x, v.y, v.z, v.w};
            #pragma unroll
            for (int s = 0; s < 4; ++s) {
                float yv = (f[s] - mu) * rs * ga + be;
                float r  = fmaxf(yv, 0.f);
                float h2 = fminf(r * r, a_c);
                o[s] = (h16)rintf(h2 * S);
            }
            *(h16x4*)&T[ci][((j + ci) & 15) * 4] = o;   // rotated column block
        }
    }
    __syncthreads();

    int c = t;
    qrow[c] = (h16)0.f;                          // left halo col (w=0)
    qrow[(P_ - 1) * C_ + c] = (h16)0.f;          // right halo col (w=57)
    #pragma unroll
    for (int jb = 0; jb < 14; ++jb) {
        h16x4 v = *(const h16x4*)&T[c][((jb + c) & 15) * 4];
        #pragma unroll
        for (int s = 0; s < 4; ++s)
            qrow[(jb * 4 + s + 1) * C_ + c] = v[s];
    }
}

// ---------------------------------------------------------------------------
// Kernel 3: ternary weight prep. One block per oc. Writes wt[tap][oc][ic]
// (B^T / K-contiguous layout, values in {-1,0,+1}) and alpha[oc].
// ---------------------------------------------------------------------------
__global__ __launch_bounds__(256)
void wq_kernel(const float* __restrict__ wfp, h16* __restrict__ wt,
               float* __restrict__ alphas) {
    int oc = blockIdx.x;
    int t  = threadIdx.x;
    const float* wr = wfp + (size_t)oc * KTOT_;
    float wl[9];
    float s = 0.f;
    #pragma unroll
    for (int j = 0; j < 9; ++j) { wl[j] = wr[t + j * 256]; s += fabsf(wl[j]); }

    __shared__ float red[4];
    int lane = t & 63, wv = t >> 6;
    #pragma unroll
    for (int off = 32; off; off >>= 1) s += __shfl_down(s, off, 64);
    if (!lane) red[wv] = s;
    __syncthreads();
    float thr = 0.05f * ((red[0] + red[1] + red[2] + red[3]) / (float)KTOT_);
    __syncthreads();

    float sm = 0.f, cnt = 0.f;
    #pragma unroll
    for (int j = 0; j < 9; ++j) {
        float aw = fabsf(wl[j]);
        if (aw > thr) { sm += aw; cnt += 1.f; }
    }
    #pragma unroll
    for (int off = 32; off; off >>= 1) {
        sm  += __shfl_down(sm, off, 64);
        cnt += __shfl_down(cnt, off, 64);
    }
    __shared__ float redc[4];
    if (!lane) { red[wv] = sm; redc[wv] = cnt; }
    __syncthreads();
    if (t == 0) {
        float alpha = (red[0] + red[1] + red[2] + red[3]) /
                      (redc[0] + redc[1] + redc[2] + redc[3] + 1e-8f);
        alphas[oc] = alpha;
    }
    #pragma unroll
    for (int j = 0; j < 9; ++j) {
        int i  = t + j * 256;           // i = ic*9 + tap
        int ic = i / 9;
        int tap = i - ic * 9;
        float w = wl[j];
        float tern = (fabsf(w) > thr) ? (w > 0.f ? 1.f : -1.f) : 0.f;
        wt[((size_t)tap * 256 + oc) * 256 + ic] = (h16)tern;
    }
}

// ---------------------------------------------------------------------------
// Kernel 4: implicit-GEMM conv. M=100352 (b,h,w), N=256 (oc), K=9*256.
// 128x128 block tile, BK=64, 4 waves (2x2 of 64x64), 16x16x32 f16 MFMA.
// Staging via global_load_lds width=16 with XOR bank swizzle: LDS column
// block kb_slot holds global K-block kb_slot ^ (row & 7), so fragment reads
// (row-stride 128B == 0 mod 32 banks) spread across all 32 banks.
// ---------------------------------------------------------------------------
__global__ __launch_bounds__(256)
void conv_gemm_kernel(const h16* __restrict__ q, const h16* __restrict__ wt,
                      const float* __restrict__ alphas, const float* __restrict__ bias,
                      const float* __restrict__ a_ptr, float* __restrict__ out) {
    int bid = blockIdx.x;
    int nt = bid & 1;            // 2 N-tiles of 128
    int mt = bid >> 1;           // 784 M-tiles of 128
    int tid = threadIdx.x;
    int lane = tid & 63;
    int wv = tid >> 6;
    int wm = wv & 1, wn = wv >> 1;
    int quad = lane >> 4, lrow = lane & 15;

    __shared__ h16 As[128 * 64];
    __shared__ h16 Bs[128 * 64];

    // XOR-swizzled global K-offset for this lane's LDS slot
    int kswz = (((tid & 7) ^ ((tid >> 3) & 7)) << 3);
    int sb[4], wb[4];
    #pragma unroll
    for (int r = 0; r < 4; ++r) {
        int ml = r * 32 + (tid >> 3);
        int m = mt * 128 + ml;
        int b = m / HW_;
        int rem = m - b * HW_;
        int hh = rem / W_;
        int ww = rem - hh * W_;
        sb[r] = ((b * P_ + hh + 1) * P_ + (ww + 1)) * C_ + kswz;
        wb[r] = (nt * 128 + ml) * C_ + kswz;
    }

    f32x4 acc[4][4];
    #pragma unroll
    for (int i = 0; i < 4; ++i)
        #pragma unroll
        for (int j = 0; j < 4; ++j) { acc[i][j][0]=0.f; acc[i][j][1]=0.f; acc[i][j][2]=0.f; acc[i][j][3]=0.f; }

    int arow = wm * 64 + lrow;   // base rows for fragment reads
    int brow = wn * 64 + lrow;
    int rsw = lrow & 7;          // read-side XOR key (row & 7 == lrow & 7)

    for (int kk = 0; kk < 36; ++kk) {
        int tap = kk >> 2;
        int ic0 = (kk & 3) << 6;
        int dh = tap / 3 - 1;
        int dw = tap - (tap / 3) * 3 - 1;
        int aoff = (dh * P_ + dw) * C_ + ic0;
        const h16* gb = wt + (size_t)tap * (256 * 256) + ic0;
        #pragma unroll
        for (int r = 0; r < 4; ++r) {
            __builtin_amdgcn_global_load_lds(
                (const __attribute__((address_space(1))) void*)(q + sb[r] + aoff),
                (__attribute__((address_space(3))) void*)(&As[r * 2048 + tid * 8]),
                16, 0, 0);
        }
        #pragma unroll
        for (int r = 0; r < 4; ++r) {
            __builtin_amdgcn_global_load_lds(
                (const __attribute__((address_space(1))) void*)(gb + wb[r]),
                (__attribute__((address_space(3))) void*)(&Bs[r * 2048 + tid * 8]),
                16, 0, 0);
        }
        __syncthreads();
        #pragma unroll
        for (int ks = 0; ks < 2; ++ks) {
            half8 af[4], bf[4];
            #pragma unroll
            for (int mi = 0; mi < 4; ++mi) {
                int cb = (ks * 4 + quad) ^ rsw;
                af[mi] = *(const half8*)&As[(arow + mi * 16) * 64 + cb * 8];
            }
            #pragma unroll
            for (int ni = 0; ni < 4; ++ni) {
                int cb = (ks * 4 + quad) ^ rsw;
                bf[ni] = *(const half8*)&Bs[(brow + ni * 16) * 64 + cb * 8];
            }
            #pragma unroll
            for (int mi = 0; mi < 4; ++mi)
                #pragma unroll
                for (int ni = 0; ni < 4; ++ni)
                    acc[mi][ni] = __builtin_amdgcn_mfma_f32_16x16x32_f16(
                        af[mi], bf[ni], acc[mi][ni], 0, 0, 0);
        }
        __syncthreads();
    }

    float a_c = fmaxf(a_ptr[0], 0.f) + 1e-8f;
    float qs  = a_c * (1.f / 255.f);
    #pragma unroll
    for (int ni = 0; ni < 4; ++ni) {
        int n = nt * 128 + wn * 64 + ni * 16 + lrow;
        float sc = alphas[n] * qs;
        float bn = bias[n];
        #pragma unroll
        for (int mi = 0; mi < 4; ++mi) {
            int mbase = mt * 128 + wm * 64 + mi * 16 + quad * 4;
            int b = mbase / HW_;
            size_t off = (size_t)b * (C_ * HW_) + (size_t)n * HW_ + (mbase - b * HW_);
            f32x4 v;
            #pragma unroll
            for (int r = 0; r < 4; ++r) v[r] = acc[mi][ni][r] * sc + bn;
            *(f32x4*)(out + off) = v;
        }
    }
}

// ---------------------------------------------------------------------------
extern "C" void kernel_launch(void* const* d_in, const int* in_sizes, int n_in,
                              void* d_out, int out_size, void* d_ws, size_t ws_size,
                              hipStream_t stream) {
    const float* x     = (const float*)d_in[0];
    const float* gamma = (const float*)d_in[1];
    const float* beta  = (const float*)d_in[2];
    const float* a     = (const float*)d_in[3];
    const float* wfp   = (const float*)d_in[4];
    const float* bias  = (const float*)d_in[5];
    float* out = (float*)d_out;

    char* ws = (char*)d_ws;
    h16*  qbuf   = (h16*)ws;                                   // 32*58*58*256 fp16 = 55,115,776 B
    h16*  wtb    = (h16*)(ws + 55115776);                      // 9*256*256 fp16  = 1,179,648 B
    float* alphas = (float*)(ws + 55115776 + 1179648);         // 256 fp32
    float* stats  = alphas + 256;                              // 512 fp32 (mu, rs)

    gn_stats_kernel<<<B_ * G_, 256, 0, stream>>>(x, stats);
    wq_kernel<<<COUT_, 256, 0, stream>>>(wfp, wtb, alphas);
    act_kernel<<<B_ * P_, 256, 0, stream>>>(x, gamma, beta, a, stats, qbuf);
    conv_gemm_kernel<<<784 * 2, 256, 0, stream>>>(qbuf, wtb, alphas, bias, a, out);
}

// Round 3
// 325.722 us; speedup vs baseline: 1.4736x; 1.3016x over previous
//
#include <hip/hip_runtime.h>
#include <hip/hip_bf16.h>

#define B_    32
#define C_    256
#define H_    56
#define W_    56
#define HW_   3136
#define P_    58          // padded spatial (halo of 1)
#define G_    8
#define COUT_ 256
#define KTOT_ 2304        // 256 * 9

typedef _Float16 h16;
typedef _Float16 half8 __attribute__((ext_vector_type(8)));
typedef _Float16 h16x4 __attribute__((ext_vector_type(4)));
typedef float    f32x4 __attribute__((ext_vector_type(4)));

// ---------------------------------------------------------------------------
// Kernel 1: GroupNorm statistics. One block per (b,g); 1024 threads
// (16 waves -> 4 waves/SIMD) for memory-level parallelism on the 400KB/block
// contiguous read. Group data is contiguous in NCHW (32 consecutive chans).
// ---------------------------------------------------------------------------
__global__ __launch_bounds__(1024)
void gn_stats_kernel(const float* __restrict__ x, float* __restrict__ stats) {
    int bg = blockIdx.x;                       // b*8 + g
    const float4* base = (const float4*)(x + (size_t)bg * (32 * HW_));
    float s1 = 0.f, s2 = 0.f;
    for (int i = threadIdx.x; i < 25088; i += 1024) {   // 100352 floats / 4
        float4 v = base[i];
        s1 += v.x + v.y + v.z + v.w;
        s2 += v.x * v.x + v.y * v.y + v.z * v.z + v.w * v.w;
    }
    #pragma unroll
    for (int off = 32; off; off >>= 1) {
        s1 += __shfl_down(s1, off, 64);
        s2 += __shfl_down(s2, off, 64);
    }
    __shared__ float ra[16], rb[16];
    int lane = threadIdx.x & 63, wv = threadIdx.x >> 6;
    if (!lane) { ra[wv] = s1; rb[wv] = s2; }
    __syncthreads();
    if (threadIdx.x == 0) {
        float t1 = 0.f, t2 = 0.f;
        #pragma unroll
        for (int i = 0; i < 16; ++i) { t1 += ra[i]; t2 += rb[i]; }
        float mu = t1 / 100352.f;
        float var = t2 / 100352.f - mu * mu;
        stats[bg * 2]     = mu;
        stats[bg * 2 + 1] = rsqrtf(var + 1e-5f);
    }
}

// ---------------------------------------------------------------------------
// Kernel 2: GN + ReLU^2 + PACT quant -> zero-padded NHWC fp16 q buffer.
// Coalesced float4 reads of x (wave = 4 channels x 14 float4-lanes), LDS
// transpose tile T[c][64] with +c rotation swizzle on 4-column blocks,
// coalesced 512B-contiguous output rows. q holds INTEGERS 0..255 (exact in
// fp16); halo rows/cols are 0 so the GEMM needs no masking.
// ---------------------------------------------------------------------------
__global__ __launch_bounds__(256)
void act_kernel(const float* __restrict__ x, const float* __restrict__ gamma,
                const float* __restrict__ beta, const float* __restrict__ a_ptr,
                const float* __restrict__ stats, h16* __restrict__ q) {
    int by = blockIdx.x;                 // b*58 + y
    int b = by / P_;
    int y = by - b * P_;
    h16* qrow = q + (size_t)by * P_ * C_;
    if (y == 0 || y == P_ - 1) {
        for (int i = threadIdx.x; i < P_ * C_; i += 256) qrow[i] = (h16)0.f;
        return;
    }
    __shared__ h16 T[256][64];           // [channel][w-blocks, rotated]

    int t = threadIdx.x;
    float a_c = fmaxf(a_ptr[0], 0.f) + 1e-8f;
    float S   = 255.f / a_c;

    int j  = t & 15;                     // float4 index along w (0..13 active)
    int cb = t >> 4;                     // channel sub-block 0..15
    #pragma unroll 4
    for (int iter = 0; iter < 16; ++iter) {
        int ci = iter * 16 + cb;
        if (j < 14) {
            int g = ci >> 5;
            float mu = stats[(b * G_ + g) * 2];
            float rs = stats[(b * G_ + g) * 2 + 1];
            float ga = gamma[ci], be = beta[ci];
            const float4* xr = (const float4*)(x + ((size_t)(b * C_ + ci)) * HW_ + (y - 1) * W_);
            float4 v = xr[j];
            h16x4 o;
            float f[4] = {v.x, v.y, v.z, v.w};
            #pragma unroll
            for (int s = 0; s < 4; ++s) {
                float yv = (f[s] - mu) * rs * ga + be;
                float r  = fmaxf(yv, 0.f);
                float h2 = fminf(r * r, a_c);
                o[s] = (h16)rintf(h2 * S);
            }
            *(h16x4*)&T[ci][((j + ci) & 15) * 4] = o;   // rotated column block
        }
    }
    __syncthreads();

    int c = t;
    qrow[c] = (h16)0.f;                          // left halo col (w=0)
    qrow[(P_ - 1) * C_ + c] = (h16)0.f;          // right halo col (w=57)
    #pragma unroll
    for (int jb = 0; jb < 14; ++jb) {
        h16x4 v = *(const h16x4*)&T[c][((jb + c) & 15) * 4];
        #pragma unroll
        for (int s = 0; s < 4; ++s)
            qrow[(jb * 4 + s + 1) * C_ + c] = v[s];
    }
}

// ---------------------------------------------------------------------------
// Kernel 3: ternary weight prep. One block per oc. Writes wt[tap][oc][ic]
// (B^T / K-contiguous layout, values in {-1,0,+1}) and alpha[oc].
// ---------------------------------------------------------------------------
__global__ __launch_bounds__(256)
void wq_kernel(const float* __restrict__ wfp, h16* __restrict__ wt,
               float* __restrict__ alphas) {
    int oc = blockIdx.x;
    int t  = threadIdx.x;
    const float* wr = wfp + (size_t)oc * KTOT_;
    float wl[9];
    float s = 0.f;
    #pragma unroll
    for (int j = 0; j < 9; ++j) { wl[j] = wr[t + j * 256]; s += fabsf(wl[j]); }

    __shared__ float red[4];
    int lane = t & 63, wv = t >> 6;
    #pragma unroll
    for (int off = 32; off; off >>= 1) s += __shfl_down(s, off, 64);
    if (!lane) red[wv] = s;
    __syncthreads();
    float thr = 0.05f * ((red[0] + red[1] + red[2] + red[3]) / (float)KTOT_);
    __syncthreads();

    float sm = 0.f, cnt = 0.f;
    #pragma unroll
    for (int j = 0; j < 9; ++j) {
        float aw = fabsf(wl[j]);
        if (aw > thr) { sm += aw; cnt += 1.f; }
    }
    #pragma unroll
    for (int off = 32; off; off >>= 1) {
        sm  += __shfl_down(sm, off, 64);
        cnt += __shfl_down(cnt, off, 64);
    }
    __shared__ float redc[4];
    if (!lane) { red[wv] = sm; redc[wv] = cnt; }
    __syncthreads();
    if (t == 0) {
        float alpha = (red[0] + red[1] + red[2] + red[3]) /
                      (redc[0] + redc[1] + redc[2] + redc[3] + 1e-8f);
        alphas[oc] = alpha;
    }
    #pragma unroll
    for (int j = 0; j < 9; ++j) {
        int i  = t + j * 256;           // i = ic*9 + tap
        int ic = i / 9;
        int tap = i - ic * 9;
        float w = wl[j];
        float tern = (fabsf(w) > thr) ? (w > 0.f ? 1.f : -1.f) : 0.f;
        wt[((size_t)tap * 256 + oc) * 256 + ic] = (h16)tern;
    }
}

// ---------------------------------------------------------------------------
// Kernel 4: implicit-GEMM conv, FULL-N blocks. M=100352, N=256 (whole N per
// block), K=9*256. 128x256 block tile, BK=64, 512 threads = 8 waves (2x4 of
// 64x64), 16x16x32 f16 MFMA. A staged ONCE per block for all 256 oc (halves
// A restaging vs 128x128). LDS 48KB -> 3 blocks/CU = 24 waves/CU.
// XOR bank swizzle on K-blocks: slot kb holds global kb ^ (row&7); fragment
// reads at (ks*4+quad)^(lrow&7) -> conflict-free (verified 4.3e7 -> 0 in R2).
// ---------------------------------------------------------------------------
__global__ __launch_bounds__(512)
void conv_gemm_kernel(const h16* __restrict__ q, const h16* __restrict__ wt,
                      const float* __restrict__ alphas, const float* __restrict__ bias,
                      const float* __restrict__ a_ptr, float* __restrict__ out) {
    int mt = blockIdx.x;         // 784 M-tiles of 128
    int tid = threadIdx.x;       // 0..511
    int lane = tid & 63;
    int wv = tid >> 6;           // 0..7
    int wm = wv & 1, wn = wv >> 1;          // 2 m-halves x 4 n-quarters
    int quad = lane >> 4, lrow = lane & 15;

    __shared__ h16 As[128 * 64];   // 16 KB
    __shared__ h16 Bs[256 * 64];   // 32 KB

    // XOR-swizzled global K-offset for this lane's LDS slot (row&7 == (tid>>3)&7)
    int kswz = (((tid & 7) ^ ((tid >> 3) & 7)) << 3);
    int sb[2], wb[4];
    #pragma unroll
    for (int r = 0; r < 2; ++r) {
        int ml = r * 64 + (tid >> 3);
        int m = mt * 128 + ml;
        int b = m / HW_;
        int rem = m - b * HW_;
        int hh = rem / W_;
        int ww = rem - hh * W_;
        sb[r] = ((b * P_ + hh + 1) * P_ + (ww + 1)) * C_ + kswz;
    }
    #pragma unroll
    for (int r = 0; r < 4; ++r) {
        int oc = r * 64 + (tid >> 3);
        wb[r] = oc * C_ + kswz;
    }

    f32x4 acc[4][4];
    #pragma unroll
    for (int i = 0; i < 4; ++i)
        #pragma unroll
        for (int j = 0; j < 4; ++j) { acc[i][j][0]=0.f; acc[i][j][1]=0.f; acc[i][j][2]=0.f; acc[i][j][3]=0.f; }

    int arow = wm * 64 + lrow;   // base rows for fragment reads
    int brow = wn * 64 + lrow;
    int rsw = lrow & 7;          // read-side XOR key

    for (int kk = 0; kk < 36; ++kk) {
        int tap = kk >> 2;
        int ic0 = (kk & 3) << 6;
        int dh = tap / 3 - 1;
        int dw = tap - (tap / 3) * 3 - 1;
        int aoff = (dh * P_ + dw) * C_ + ic0;
        const h16* gb = wt + (size_t)tap * (256 * 256) + ic0;
        #pragma unroll
        for (int r = 0; r < 2; ++r) {
            __builtin_amdgcn_global_load_lds(
                (const __attribute__((address_space(1))) void*)(q + sb[r] + aoff),
                (__attribute__((address_space(3))) void*)(&As[r * 4096 + tid * 8]),
                16, 0, 0);
        }
        #pragma unroll
        for (int r = 0; r < 4; ++r) {
            __builtin_amdgcn_global_load_lds(
                (const __attribute__((address_space(1))) void*)(gb + wb[r]),
                (__attribute__((address_space(3))) void*)(&Bs[r * 4096 + tid * 8]),
                16, 0, 0);
        }
        __syncthreads();
        #pragma unroll
        for (int ks = 0; ks < 2; ++ks) {
            int cb = (ks * 4 + quad) ^ rsw;
            half8 af[4], bf[4];
            #pragma unroll
            for (int mi = 0; mi < 4; ++mi)
                af[mi] = *(const half8*)&As[(arow + mi * 16) * 64 + cb * 8];
            #pragma unroll
            for (int ni = 0; ni < 4; ++ni)
                bf[ni] = *(const half8*)&Bs[(brow + ni * 16) * 64 + cb * 8];
            #pragma unroll
            for (int mi = 0; mi < 4; ++mi)
                #pragma unroll
                for (int ni = 0; ni < 4; ++ni)
                    acc[mi][ni] = __builtin_amdgcn_mfma_f32_16x16x32_f16(
                        af[mi], bf[ni], acc[mi][ni], 0, 0, 0);
        }
        __syncthreads();
    }

    float a_c = fmaxf(a_ptr[0], 0.f) + 1e-8f;
    float qs  = a_c * (1.f / 255.f);
    #pragma unroll
    for (int ni = 0; ni < 4; ++ni) {
        int n = wn * 64 + ni * 16 + lrow;
        float sc = alphas[n] * qs;
        float bn = bias[n];
        #pragma unroll
        for (int mi = 0; mi < 4; ++mi) {
            int mbase = mt * 128 + wm * 64 + mi * 16 + quad * 4;
            int b = mbase / HW_;
            size_t off = (size_t)b * (C_ * HW_) + (size_t)n * HW_ + (mbase - b * HW_);
            f32x4 v;
            #pragma unroll
            for (int r = 0; r < 4; ++r) v[r] = acc[mi][ni][r] * sc + bn;
            *(f32x4*)(out + off) = v;
        }
    }
}

// ---------------------------------------------------------------------------
extern "C" void kernel_launch(void* const* d_in, const int* in_sizes, int n_in,
                              void* d_out, int out_size, void* d_ws, size_t ws_size,
                              hipStream_t stream) {
    const float* x     = (const float*)d_in[0];
    const float* gamma = (const float*)d_in[1];
    const float* beta  = (const float*)d_in[2];
    const float* a     = (const float*)d_in[3];
    const float* wfp   = (const float*)d_in[4];
    const float* bias  = (const float*)d_in[5];
    float* out = (float*)d_out;

    char* ws = (char*)d_ws;
    h16*  qbuf   = (h16*)ws;                                   // 32*58*58*256 fp16 = 55,115,776 B
    h16*  wtb    = (h16*)(ws + 55115776);                      // 9*256*256 fp16  = 1,179,648 B
    float* alphas = (float*)(ws + 55115776 + 1179648);         // 256 fp32
    float* stats  = alphas + 256;                              // 512 fp32 (mu, rs)

    gn_stats_kernel<<<B_ * G_, 1024, 0, stream>>>(x, stats);
    wq_kernel<<<COUT_, 256, 0, stream>>>(wfp, wtb, alphas);
    act_kernel<<<B_ * P_, 256, 0, stream>>>(x, gamma, beta, a, stats, qbuf);
    conv_gemm_kernel<<<784, 512, 0, stream>>>(qbuf, wtb, alphas, bias, a, out);
}

// Round 4
// 290.783 us; speedup vs baseline: 1.6506x; 1.1202x over previous
//
#include <hip/hip_runtime.h>
#include <hip/hip_bf16.h>

#define B_    32
#define C_    256
#define H_    56
#define W_    56
#define HW_   3136
#define P_    58          // padded spatial (halo of 1)
#define G_    8
#define COUT_ 256
#define KTOT_ 2304        // 256 * 9

typedef float f32x4 __attribute__((ext_vector_type(4)));
typedef int   i32x4 __attribute__((ext_vector_type(4)));

// ---------------------------------------------------------------------------
// Kernel 1: GroupNorm statistics. One block per (b,g); 1024 threads
// (16 waves -> 4 waves/SIMD) for MLP on the 400KB/block contiguous read.
// ---------------------------------------------------------------------------
__global__ __launch_bounds__(1024)
void gn_stats_kernel(const float* __restrict__ x, float* __restrict__ stats) {
    int bg = blockIdx.x;                       // b*8 + g
    const float4* base = (const float4*)(x + (size_t)bg * (32 * HW_));
    float s1 = 0.f, s2 = 0.f;
    for (int i = threadIdx.x; i < 25088; i += 1024) {   // 100352 floats / 4
        float4 v = base[i];
        s1 += v.x + v.y + v.z + v.w;
        s2 += v.x * v.x + v.y * v.y + v.z * v.z + v.w * v.w;
    }
    #pragma unroll
    for (int off = 32; off; off >>= 1) {
        s1 += __shfl_down(s1, off, 64);
        s2 += __shfl_down(s2, off, 64);
    }
    __shared__ float ra[16], rb[16];
    int lane = threadIdx.x & 63, wv = threadIdx.x >> 6;
    if (!lane) { ra[wv] = s1; rb[wv] = s2; }
    __syncthreads();
    if (threadIdx.x == 0) {
        float t1 = 0.f, t2 = 0.f;
        #pragma unroll
        for (int i = 0; i < 16; ++i) { t1 += ra[i]; t2 += rb[i]; }
        float mu = t1 / 100352.f;
        float var = t2 / 100352.f - mu * mu;
        stats[bg * 2]     = mu;
        stats[bg * 2 + 1] = rsqrtf(var + 1e-5f);
    }
}

// ---------------------------------------------------------------------------
// Kernel 2 (v3): GN + ReLU^2 + PACT quant -> zero-padded NHWC int8 buffer.
// Stores qs = round(q) - 128 in [-128,127]; halo = -128 (consistent with the
// epilogue correction  sum(q*t) = acc + 128*T[oc]).  Register 4x4 transpose:
// thread owns 4 channels (c4 = tid&63; wave spans all 256 ch) x float4
// w-blocks; stores are packed 4B ints, 256B contiguous per wave instruction.
// ---------------------------------------------------------------------------
__global__ __launch_bounds__(256)
void act_kernel(const float* __restrict__ x, const float* __restrict__ gamma,
                const float* __restrict__ beta, const float* __restrict__ a_ptr,
                const float* __restrict__ stats, char* __restrict__ q) {
    int by = blockIdx.x;                 // b*58 + y
    int b = by / P_;
    int y = by - b * P_;
    char* qrow = q + (size_t)by * P_ * C_;
    const int PADV = 0x80808080;         // four -128 bytes
    if (y == 0 || y == P_ - 1) {
        int4 pv = {PADV, PADV, PADV, PADV};
        for (int i = threadIdx.x; i < (P_ * C_) / 16; i += 256)
            ((int4*)qrow)[i] = pv;
        return;
    }
    int t = threadIdx.x;
    // halo columns (pixel 0 and 57): 64 ints each
    if (t < 64)            ((int*)qrow)[t] = PADV;
    else if (t < 128)      ((int*)(qrow + (P_ - 1) * C_))[t - 64] = PADV;

    float a_c = fmaxf(a_ptr[0], 0.f) + 1e-8f;
    float S   = 255.f / a_c;

    int c4 = t & 63;                     // channels 4*c4 .. 4*c4+3 (same group)
    int wb = t >> 6;                     // starting w-block
    int g  = (4 * c4) >> 5;
    float mu = stats[(b * G_ + g) * 2];
    float rs = stats[(b * G_ + g) * 2 + 1];
    float ga[4], be[4];
    #pragma unroll
    for (int i = 0; i < 4; ++i) { ga[i] = gamma[4 * c4 + i]; be[i] = beta[4 * c4 + i]; }

    const float* xb = x + ((size_t)(b * C_ + 4 * c4)) * HW_ + (y - 1) * W_;
    for (int j = wb; j < 14; j += 4) {
        float4 v[4];
        #pragma unroll
        for (int i = 0; i < 4; ++i)
            v[i] = *(const float4*)(xb + (size_t)i * HW_ + j * 4);
        int qv[4][4];
        #pragma unroll
        for (int i = 0; i < 4; ++i) {
            float f[4] = {v[i].x, v[i].y, v[i].z, v[i].w};
            #pragma unroll
            for (int s = 0; s < 4; ++s) {
                float yv = (f[s] - mu) * rs * ga[i] + be[i];
                float r  = fmaxf(yv, 0.f);
                float h2 = fminf(r * r, a_c);
                qv[i][s] = (int)rintf(h2 * S) - 128;
            }
        }
        #pragma unroll
        for (int s = 0; s < 4; ++s) {
            int packed = (qv[0][s] & 255) | ((qv[1][s] & 255) << 8) |
                         ((qv[2][s] & 255) << 16) | (qv[3][s] << 24);
            *(int*)(qrow + (j * 4 + s + 1) * C_ + 4 * c4) = packed;
        }
    }
}

// ---------------------------------------------------------------------------
// Kernel 3: ternary weight prep. One block per oc. Writes wt[tap][oc][ic]
// as int8 {-1,0,+1}, alpha[oc], and tsum[oc] = sum_k t[oc,k] (epilogue
// correction for the -128 activation shift).
// ---------------------------------------------------------------------------
__global__ __launch_bounds__(256)
void wq_kernel(const float* __restrict__ wfp, char* __restrict__ wt,
               float* __restrict__ alphas, float* __restrict__ tsum) {
    int oc = blockIdx.x;
    int t  = threadIdx.x;
    const float* wr = wfp + (size_t)oc * KTOT_;
    float wl[9];
    float s = 0.f;
    #pragma unroll
    for (int j = 0; j < 9; ++j) { wl[j] = wr[t + j * 256]; s += fabsf(wl[j]); }

    __shared__ float red[4];
    int lane = t & 63, wv = t >> 6;
    #pragma unroll
    for (int off = 32; off; off >>= 1) s += __shfl_down(s, off, 64);
    if (!lane) red[wv] = s;
    __syncthreads();
    float thr = 0.05f * ((red[0] + red[1] + red[2] + red[3]) / (float)KTOT_);
    __syncthreads();

    float sm = 0.f, cnt = 0.f, ts = 0.f;
    #pragma unroll
    for (int j = 0; j < 9; ++j) {
        float aw = fabsf(wl[j]);
        if (aw > thr) {
            sm += aw; cnt += 1.f;
            ts += (wl[j] > 0.f) ? 1.f : -1.f;
        }
    }
    #pragma unroll
    for (int off = 32; off; off >>= 1) {
        sm  += __shfl_down(sm, off, 64);
        cnt += __shfl_down(cnt, off, 64);
        ts  += __shfl_down(ts, off, 64);
    }
    __shared__ float redc[4], redt[4];
    if (!lane) { red[wv] = sm; redc[wv] = cnt; redt[wv] = ts; }
    __syncthreads();
    if (t == 0) {
        float alpha = (red[0] + red[1] + red[2] + red[3]) /
                      (redc[0] + redc[1] + redc[2] + redc[3] + 1e-8f);
        alphas[oc] = alpha;
        tsum[oc] = redt[0] + redt[1] + redt[2] + redt[3];
    }
    #pragma unroll
    for (int j = 0; j < 9; ++j) {
        int i  = t + j * 256;           // i = ic*9 + tap
        int ic = i / 9;
        int tap = i - ic * 9;
        float w = wl[j];
        char tern = (fabsf(w) > thr) ? (w > 0.f ? (char)1 : (char)-1) : (char)0;
        wt[((size_t)tap * 256 + oc) * 256 + ic] = tern;
    }
}

// ---------------------------------------------------------------------------
// Kernel 4: implicit-GEMM conv, i8 MFMA. M=100352, N=256 (full N per block),
// K=9*256. 128x256 block tile, BK=128 (one i8 = half the bytes of f16 BK=64:
// SAME 128B LDS rows, SAME XOR swizzle, half the K-iterations: 18 vs 36).
// 512 threads = 8 waves (2x4 of 64x64), mfma_i32_16x16x64_i8 (2x f16 rate).
// Exact integer arithmetic; epilogue adds 128*tsum[oc] shift correction.
// ---------------------------------------------------------------------------
__global__ __launch_bounds__(512)
void conv_gemm_kernel(const char* __restrict__ q, const char* __restrict__ wt,
                      const float* __restrict__ alphas, const float* __restrict__ bias,
                      const float* __restrict__ tsum, const float* __restrict__ a_ptr,
                      float* __restrict__ out) {
    int mt = blockIdx.x;         // 784 M-tiles of 128
    int tid = threadIdx.x;       // 0..511
    int lane = tid & 63;
    int wv = tid >> 6;           // 0..7
    int wm = wv & 1, wn = wv >> 1;          // 2 m-halves x 4 n-quarters
    int quad = lane >> 4, lrow = lane & 15;

    __shared__ char As[128 * 128];   // 16 KB
    __shared__ char Bs[256 * 128];   // 32 KB

    // XOR bank swizzle on 16B K-blocks: slot kb holds global kb ^ (row&7)
    int kswz = (((tid & 7) ^ ((tid >> 3) & 7)) << 4);
    int sb[2], wb[4];
    #pragma unroll
    for (int r = 0; r < 2; ++r) {
        int ml = r * 64 + (tid >> 3);
        int m = mt * 128 + ml;
        int b = m / HW_;
        int rem = m - b * HW_;
        int hh = rem / W_;
        int ww = rem - hh * W_;
        sb[r] = ((b * P_ + hh + 1) * P_ + (ww + 1)) * C_ + kswz;
    }
    #pragma unroll
    for (int r = 0; r < 4; ++r) {
        int oc = r * 64 + (tid >> 3);
        wb[r] = oc * C_ + kswz;
    }

    i32x4 acc[4][4];
    #pragma unroll
    for (int i = 0; i < 4; ++i)
        #pragma unroll
        for (int j = 0; j < 4; ++j) { acc[i][j][0]=0; acc[i][j][1]=0; acc[i][j][2]=0; acc[i][j][3]=0; }

    int arow = wm * 64 + lrow;
    int brow = wn * 64 + lrow;
    int rsw = lrow & 7;          // read-side XOR key

    for (int kk = 0; kk < 18; ++kk) {
        int tap = kk >> 1;
        int ic0 = (kk & 1) << 7;
        int dh = tap / 3 - 1;
        int dw = tap - (tap / 3) * 3 - 1;
        int aoff = (dh * P_ + dw) * C_ + ic0;
        const char* gb = wt + (size_t)tap * (256 * 256) + ic0;
        #pragma unroll
        for (int r = 0; r < 2; ++r) {
            __builtin_amdgcn_global_load_lds(
                (const __attribute__((address_space(1))) void*)(q + sb[r] + aoff),
                (__attribute__((address_space(3))) void*)(&As[r * 8192 + tid * 16]),
                16, 0, 0);
        }
        #pragma unroll
        for (int r = 0; r < 4; ++r) {
            __builtin_amdgcn_global_load_lds(
                (const __attribute__((address_space(1))) void*)(gb + wb[r]),
                (__attribute__((address_space(3))) void*)(&Bs[r * 8192 + tid * 16]),
                16, 0, 0);
        }
        __syncthreads();
        #pragma unroll
        for (int ks = 0; ks < 2; ++ks) {
            int cb = (ks * 4 + quad) ^ rsw;
            i32x4 af[4], bf[4];
            #pragma unroll
            for (int mi = 0; mi < 4; ++mi)
                af[mi] = *(const i32x4*)&As[(arow + mi * 16) * 128 + cb * 16];
            #pragma unroll
            for (int ni = 0; ni < 4; ++ni)
                bf[ni] = *(const i32x4*)&Bs[(brow + ni * 16) * 128 + cb * 16];
            #pragma unroll
            for (int mi = 0; mi < 4; ++mi)
                #pragma unroll
                for (int ni = 0; ni < 4; ++ni)
                    acc[mi][ni] = __builtin_amdgcn_mfma_i32_16x16x64_i8(
                        af[mi], bf[ni], acc[mi][ni], 0, 0, 0);
        }
        __syncthreads();
    }

    float a_c = fmaxf(a_ptr[0], 0.f) + 1e-8f;
    float qs  = a_c * (1.f / 255.f);
    #pragma unroll
    for (int ni = 0; ni < 4; ++ni) {
        int n = wn * 64 + ni * 16 + lrow;
        float sc = alphas[n] * qs;
        float bn = bias[n];
        float corr = 128.f * tsum[n];       // undo the -128 activation shift
        #pragma unroll
        for (int mi = 0; mi < 4; ++mi) {
            int mbase = mt * 128 + wm * 64 + mi * 16 + quad * 4;
            int b = mbase / HW_;
            size_t off = (size_t)b * (C_ * HW_) + (size_t)n * HW_ + (mbase - b * HW_);
            f32x4 v;
            #pragma unroll
            for (int r = 0; r < 4; ++r)
                v[r] = ((float)acc[mi][ni][r] + corr) * sc + bn;
            *(f32x4*)(out + off) = v;
        }
    }
}

// ---------------------------------------------------------------------------
extern "C" void kernel_launch(void* const* d_in, const int* in_sizes, int n_in,
                              void* d_out, int out_size, void* d_ws, size_t ws_size,
                              hipStream_t stream) {
    const float* x     = (const float*)d_in[0];
    const float* gamma = (const float*)d_in[1];
    const float* beta  = (const float*)d_in[2];
    const float* a     = (const float*)d_in[3];
    const float* wfp   = (const float*)d_in[4];
    const float* bias  = (const float*)d_in[5];
    float* out = (float*)d_out;

    char* ws = (char*)d_ws;
    char*  qbuf   = ws;                                        // 32*58*58*256 i8 = 27,557,888 B
    char*  wtb    = ws + 27557888;                             // 9*256*256 i8  = 589,824 B
    float* alphas = (float*)(ws + 27557888 + 589824);          // 256 fp32
    float* tsum   = alphas + 256;                              // 256 fp32
    float* stats  = tsum + 256;                                // 512 fp32 (mu, rs)

    gn_stats_kernel<<<B_ * G_, 1024, 0, stream>>>(x, stats);
    wq_kernel<<<COUT_, 256, 0, stream>>>(wfp, wtb, alphas, tsum);
    act_kernel<<<B_ * P_, 256, 0, stream>>>(x, gamma, beta, a, stats, qbuf);
    conv_gemm_kernel<<<784, 512, 0, stream>>>(qbuf, wtb, alphas, bias, tsum, a, out);
}